// Round 3
// baseline (1588.193 us; speedup 1.0000x reference)
//
#include <hip/hip_runtime.h>
#include <math.h>

#define N_NODES 100000
#define N_EDGES 1600000
#define NODE_F  64
#define IN_DIM  160          // 2*64 + 32
#define N_TILES 25000        // N_EDGES / 64
#define ZSTRIDE 168          // bf16 elems per z-row in LDS (336 B, 16B-aligned)
#define GRID    1536         // 6 blocks/CU x 256 CUs -- ALL co-resident
#define BLOCK   256

typedef __attribute__((ext_vector_type(8))) short short8;   // 8 bf16 = 4 VGPRs
typedef __attribute__((ext_vector_type(4))) float f32x4;

// round-to-nearest-even f32 -> bf16 bits (scalar; used only in W staging)
static __device__ inline unsigned short f2bf(float f) {
    union { float f; unsigned u; } v; v.f = f;
    unsigned r = v.u + 0x7fffu + ((v.u >> 16) & 1u);
    return (unsigned short)(r >> 16);
}

// RNE-round two f32 and pack their high halves into one dword.
static __device__ inline unsigned pack2(float lo, float hi) {
    union { float f; unsigned u; } a, b; a.f = lo; b.f = hi;
    const unsigned ra = a.u + 0x7fffu + ((a.u >> 16) & 1u);
    const unsigned rb = b.u + 0x7fffu + ((b.u >> 16) & 1u);
    return __builtin_amdgcn_perm(rb, ra, 0x07060302u);
}

// Device-wide barrier. Safe because grid == 256 CU x 6 blocks and
// launch_bounds+LDS(21.5KB)+VGPR(~40) guarantee all blocks co-resident.
// __threadfence() at agent scope on gfx950 emits the L2 writeback /
// invalidate needed for cross-XCD visibility (per-XCD L2s non-coherent);
// edge-phase atomics are device-scope (coherent at fabric) already.
static __device__ __forceinline__ void grid_sync(int* ctr) {
    __threadfence();                       // release: drain vm, wb L2
    __syncthreads();
    if (threadIdx.x == 0) {
        __hip_atomic_fetch_add(ctr, 1, __ATOMIC_ACQ_REL, __HIP_MEMORY_SCOPE_AGENT);
        int spins = 0;
        while (__hip_atomic_load(ctr, __ATOMIC_ACQUIRE, __HIP_MEMORY_SCOPE_AGENT) < GRID) {
            __builtin_amdgcn_s_sleep(8);
            if (++spins > (1 << 22)) break;   // failsafe (~1s); never hit when co-resident
        }
    }
    __syncthreads();
    __threadfence();                       // acquire: invalidate stale L1/L2
}

// ===========================================================================
// One persistent kernel: [edge gather->MFMA->atomic scatter] -> grid barrier
// -> [BN batch stats] -> grid barrier -> [BN + residual].
// Eliminates 2 kernel launches + dispatch-boundary gaps (~200+ us suspected).
// ===========================================================================
__global__ __launch_bounds__(BLOCK, 6) void fused_kernel(
    const float* __restrict__ node_attrs,
    const int*   __restrict__ edge_src,
    const int*   __restrict__ edge_tgt,
    const float* __restrict__ edge_attrs,
    const float* __restrict__ W_f, const float* __restrict__ b_f,
    const float* __restrict__ W_s, const float* __restrict__ b_s,
    const float* __restrict__ gamma,
    const float* __restrict__ beta,
    float* __restrict__ out,            // msg accumulator, then final output
    float* __restrict__ stats,          // 128 floats in ws (zeroed by memset)
    int*   __restrict__ ctr)            // 2 barrier counters in ws (zeroed)
{
    __shared__ __align__(16) short sbuf[64 * ZSTRIDE];   // 21504 B
    unsigned* sbuf32 = (unsigned*)sbuf;

    const int tid  = threadIdx.x;
    const int wave = tid >> 6;
    const int lane = tid & 63;
    const int quad = lane >> 4;       // 0..3
    const int l15  = lane & 15;

    // =====================================================================
    // Phase 1: edge gather -> bf16 z-tile -> MFMA gated MLP -> atomic scatter
    // (identical to the round-0 kernel that measured 364 us @ 6 blocks/CU)
    // =====================================================================

    // ---- Stage W_f then W_s transposed to LDS, pull B-fragments to registers.
    short8 bF[5], bS[5];
#pragma unroll
    for (int mat = 0; mat < 2; ++mat) {
        const float* W = mat ? W_s : W_f;
        __syncthreads();
        for (int idx = tid; idx < IN_DIM * 64; idx += 256) {
            const int k = idx >> 6, n = idx & 63;
            sbuf[n * ZSTRIDE + k] = (short)f2bf(W[idx]);
        }
        __syncthreads();
#pragma unroll
        for (int kc = 0; kc < 5; ++kc) {
            const short8 b = *(const short8*)&sbuf[(16 * wave + l15) * ZSTRIDE + kc * 32 + quad * 8];
            if (mat) bS[kc] = b; else bF[kc] = b;
        }
    }

    const float bias_f = b_f[16 * wave + l15];
    const float bias_s = b_s[16 * wave + l15];
    float* const msgf  = out + 16 * wave + l15;   // per-lane feature column

    // Prefetch first tile's indices.
    int srcv = edge_src[blockIdx.x * 64 + lane];
    int tgtv = edge_tgt[blockIdx.x * 64 + lane];

    for (int t = blockIdx.x; t < N_TILES; t += GRID) {
        const int e0 = t * 64;

        __syncthreads();   // protect sbuf from previous iteration's readers

        // ---- Node rows (f32 -> bf16 inline): wave w stages edges [16w,16w+16).
#pragma unroll
        for (int i = 0; i < 8; ++i) {
            const int el   = i * 2 + (quad >> 1);
            const int half = quad & 1;
            const int sl   = 16 * wave + el;
            const int ns   = __shfl(srcv, sl);
            const int nt   = __shfl(tgtv, sl);
            const int node = half ? nt : ns;
            const float4 v = *(const float4*)&node_attrs[node * 64 + l15 * 4];
            uint2 o; o.x = pack2(v.x, v.y); o.y = pack2(v.z, v.w);
            *(uint2*)&sbuf32[sl * (ZSTRIDE / 2) + half * 32 + l15 * 2] = o;
        }
        // ---- Edge attrs (f32 -> bf16 inline): 512 float4 rows of 16B each.
#pragma unroll
        for (int i = 0; i < 2; ++i) {
            const int p  = i * 256 + tid;       // 0..511
            const int el = p >> 3, g = p & 7;
            const float4 v = *(const float4*)&edge_attrs[(size_t)(e0 + el) * 32 + g * 4];
            uint2 o; o.x = pack2(v.x, v.y); o.y = pack2(v.z, v.w);
            *(uint2*)&sbuf32[el * (ZSTRIDE / 2) + 64 + g * 2] = o;
        }

        // Prefetch next tile's indices (loads overlap the MFMA section).
        const int tn = t + GRID;
        int nsrc = 0, ntgt = 0;
        if (tn < N_TILES) {
            nsrc = edge_src[tn * 64 + lane];
            ntgt = edge_tgt[tn * 64 + lane];
        }
        __syncthreads();

        // ---- MFMA: 4 m-tiles x 5 k-chunks x 2 matrices, then fused epilogue.
#pragma unroll
        for (int mt = 0; mt < 4; ++mt) {
            f32x4 accF = {0.f, 0.f, 0.f, 0.f};
            f32x4 accS = {0.f, 0.f, 0.f, 0.f};
#pragma unroll
            for (int kc = 0; kc < 5; ++kc) {
                const short8 a = *(const short8*)&sbuf[(mt * 16 + l15) * ZSTRIDE + kc * 32 + quad * 8];
                accF = __builtin_amdgcn_mfma_f32_16x16x32_bf16(a, bF[kc], accF, 0, 0, 0);
                accS = __builtin_amdgcn_mfma_f32_16x16x32_bf16(a, bS[kc], accS, 0, 0, 0);
            }
            // C/D: col = l15 (feature), row = quad*4 + r (edge within m-tile)
#pragma unroll
            for (int r = 0; r < 4; ++r) {
                const float xf = accF[r] + bias_f;
                const float xs = accS[r] + bias_s;
                const float sig = __builtin_amdgcn_rcpf(1.0f + __expf(-xf));
                const float sp  = fmaxf(xs, 0.0f) + __logf(1.0f + __expf(-fabsf(xs)));
                const float h   = sig * sp;
                const int sl    = mt * 16 + quad * 4 + r;   // edge within tile
                const int node  = __shfl(srcv, sl);
                atomicAdd(&msgf[node * 64], h);
            }
        }

        srcv = nsrc;
        tgtv = ntgt;
    }

    // =====================================================================
    // Barrier 1: all messages accumulated (fence drains atomics, inv caches)
    // =====================================================================
    grid_sync(&ctr[0]);

    // =====================================================================
    // Phase 2: BN batch stats. Grid-stride float4 sweep over msg.
    // thread (b,t): feature group c = t&15 (4 feats), row = b*16 + (t>>4),
    // stride GRID*16 rows. Block-level LDS reduce, 128 atomics per block.
    // =====================================================================
    {
        const int c  = tid & 15;
        const int r0 = blockIdx.x * 16 + (tid >> 4);
        float4 s = {0.f, 0.f, 0.f, 0.f};
        float4 q = {0.f, 0.f, 0.f, 0.f};
        for (int r = r0; r < N_NODES; r += GRID * 16) {
            const float4 v = *(const float4*)&out[(size_t)r * 64 + c * 4];
            s.x += v.x; s.y += v.y; s.z += v.z; s.w += v.w;
            q.x = fmaf(v.x, v.x, q.x);
            q.y = fmaf(v.y, v.y, q.y);
            q.z = fmaf(v.z, v.z, q.z);
            q.w = fmaf(v.w, v.w, q.w);
        }
        float4* rs = (float4*)sbuf;          // overlay: 256*16B = 4 KB
        float4* rq = rs + 256;               // next 4 KB (total 8 KB < 21.5 KB)
        rs[tid] = s;
        rq[tid] = q;
        __syncthreads();
        if (tid < 16) {
            float4 S = rs[tid];
            float4 Q = rq[tid];
#pragma unroll
            for (int k = 1; k < 16; ++k) {
                const float4 a = rs[k * 16 + tid];
                const float4 b = rq[k * 16 + tid];
                S.x += a.x; S.y += a.y; S.z += a.z; S.w += a.w;
                Q.x += b.x; Q.y += b.y; Q.z += b.z; Q.w += b.w;
            }
            atomicAdd(&stats[tid * 4 + 0], S.x);
            atomicAdd(&stats[tid * 4 + 1], S.y);
            atomicAdd(&stats[tid * 4 + 2], S.z);
            atomicAdd(&stats[tid * 4 + 3], S.w);
            atomicAdd(&stats[64 + tid * 4 + 0], Q.x);
            atomicAdd(&stats[64 + tid * 4 + 1], Q.y);
            atomicAdd(&stats[64 + tid * 4 + 2], Q.z);
            atomicAdd(&stats[64 + tid * 4 + 3], Q.w);
        }
    }

    // =====================================================================
    // Barrier 2: stats complete.
    // =====================================================================
    grid_sync(&ctr[1]);

    // =====================================================================
    // Phase 3: BN (training stats, biased var) + residual, in place.
    // =====================================================================
    {
        const float inv_n = 1.0f / (float)N_NODES;
        const int g0 = blockIdx.x * BLOCK + tid;
        for (int i = g0; i < N_NODES * NODE_F / 4; i += GRID * BLOCK) {
            const int idx = i * 4;
            const int f = idx & 63;

            const float4 m4 = *(const float4*)&out[idx];
            const float4 x4 = *(const float4*)&node_attrs[idx];

            float mean[4], rstd[4], gm[4], bt[4];
#pragma unroll
            for (int j = 0; j < 4; ++j) {
                mean[j] = stats[f + j] * inv_n;
                const float var = stats[64 + f + j] * inv_n - mean[j] * mean[j];
                rstd[j] = rsqrtf(var + 1e-5f);
                gm[j] = gamma[f + j];
                bt[j] = beta[f + j];
            }
            float4 o;
            o.x = x4.x + (m4.x - mean[0]) * rstd[0] * gm[0] + bt[0];
            o.y = x4.y + (m4.y - mean[1]) * rstd[1] * gm[1] + bt[1];
            o.z = x4.z + (m4.z - mean[2]) * rstd[2] * gm[2] + bt[2];
            o.w = x4.w + (m4.w - mean[3]) * rstd[3] * gm[3] + bt[3];
            *(float4*)&out[idx] = o;
        }
    }
}

extern "C" void kernel_launch(void* const* d_in, const int* in_sizes, int n_in,
                              void* d_out, int out_size, void* d_ws, size_t ws_size,
                              hipStream_t stream)
{
    const float* node_attrs = (const float*)d_in[0];
    const int*   edge_index = (const int*)d_in[1];   // [2, E] int32
    const float* edge_attrs = (const float*)d_in[2];
    const float* W_f   = (const float*)d_in[3];
    const float* b_f   = (const float*)d_in[4];
    const float* W_s   = (const float*)d_in[5];
    const float* b_s   = (const float*)d_in[6];
    const float* gamma = (const float*)d_in[7];
    const float* beta  = (const float*)d_in[8];

    float* out   = (float*)d_out;          // doubles as the msg accumulator
    float* stats = (float*)d_ws;           // 128 floats at ws+0
    int*   ctr   = (int*)((char*)d_ws + 512);   // 2 barrier counters

    const int* edge_src = edge_index;
    const int* edge_tgt = edge_index + N_EDGES;

    // Zero msg accumulator + stats + barrier counters (re-runs every replay).
    hipMemsetAsync(out, 0, (size_t)N_NODES * NODE_F * sizeof(float), stream);
    hipMemsetAsync(d_ws, 0, 1024, stream);

    fused_kernel<<<GRID, BLOCK, 0, stream>>>(
        node_attrs, edge_src, edge_tgt, edge_attrs,
        W_f, b_f, W_s, b_s, gamma, beta, out, stats, ctr);
}

// Round 4
// 966.323 us; speedup vs baseline: 1.6435x; 1.6435x over previous
//
#include <hip/hip_runtime.h>
#include <math.h>

#define N_NODES 100000
#define N_EDGES 1600000
#define NODE_F  64
#define IN_DIM  160          // 2*64 + 32
#define N_TILES 25000        // N_EDGES / 64
#define ZSTRIDE 168          // bf16 elems per z-row in LDS (336 B, 16B-aligned)
#define GRID    1536         // 6 blocks/CU x 256 CUs -- ALL co-resident
#define BLOCK   256

typedef __attribute__((ext_vector_type(8))) short short8;   // 8 bf16 = 4 VGPRs
typedef __attribute__((ext_vector_type(4))) float f32x4;

// round-to-nearest-even f32 -> bf16 bits (scalar; used only in W staging)
static __device__ inline unsigned short f2bf(float f) {
    union { float f; unsigned u; } v; v.f = f;
    unsigned r = v.u + 0x7fffu + ((v.u >> 16) & 1u);
    return (unsigned short)(r >> 16);
}

// RNE-round two f32 and pack their high halves into one dword.
static __device__ inline unsigned pack2(float lo, float hi) {
    union { float f; unsigned u; } a, b; a.f = lo; b.f = hi;
    const unsigned ra = a.u + 0x7fffu + ((a.u >> 16) & 1u);
    const unsigned rb = b.u + 0x7fffu + ((b.u >> 16) & 1u);
    return __builtin_amdgcn_perm(rb, ra, 0x07060302u);
}

// Device-wide barrier, cooperative-groups style.
// Round-3 post-mortem: polling with an ACQUIRE agent-scope load emits
// `s_waitcnt vmcnt(0) + buffer_inv sc1` PER POLL -- an L2 invalidate storm
// from spinning blocks that destroyed cache locality for still-working
// blocks on the same XCD (4x slowdown, no extra FETCH: latency poison).
// Correct pattern:
//   - __syncthreads() first: its vmcnt(0) drain retires every wave's
//     device-scope atomics (globally visible once retired).
//   - ONE release fetch_add per block (single wb).
//   - RELAXED polls (plain coherent load, no cache maintenance) + s_sleep.
//   - ONE acquire load after the spin: single L1/L2 invalidate so the
//     block's subsequent reads see remote atomics' results. L1 is per-CU,
//     shared by all the block's waves -> tid0's acquire + syncthreads
//     covers the whole block.
static __device__ __forceinline__ void grid_sync(int* ctr) {
    __syncthreads();   // drains vmcnt(0)/lgkmcnt(0) per wave + block sync
    if (threadIdx.x == 0) {
        __hip_atomic_fetch_add(ctr, 1, __ATOMIC_RELEASE, __HIP_MEMORY_SCOPE_AGENT);
        int spins = 0;
        while (__hip_atomic_load(ctr, __ATOMIC_RELAXED, __HIP_MEMORY_SCOPE_AGENT) < GRID) {
            __builtin_amdgcn_s_sleep(32);                  // ~2k clocks/poll
            if (++spins > (1 << 20)) break;                // ~1 s failsafe; never hit when co-resident
        }
        (void)__hip_atomic_load(ctr, __ATOMIC_ACQUIRE, __HIP_MEMORY_SCOPE_AGENT);
    }
    __syncthreads();
}

// ===========================================================================
// One persistent kernel: [edge gather->MFMA->atomic scatter] -> grid barrier
// -> [BN batch stats] -> grid barrier -> [BN + residual].
// ===========================================================================
__global__ __launch_bounds__(BLOCK, 6) void fused_kernel(
    const float* __restrict__ node_attrs,
    const int*   __restrict__ edge_src,
    const int*   __restrict__ edge_tgt,
    const float* __restrict__ edge_attrs,
    const float* __restrict__ W_f, const float* __restrict__ b_f,
    const float* __restrict__ W_s, const float* __restrict__ b_s,
    const float* __restrict__ gamma,
    const float* __restrict__ beta,
    float* __restrict__ out,            // msg accumulator, then final output
    float* __restrict__ stats,          // 128 floats in ws (zeroed by memset)
    int*   __restrict__ ctr)            // 2 barrier counters in ws (zeroed)
{
    __shared__ __align__(16) short sbuf[64 * ZSTRIDE];   // 21504 B
    unsigned* sbuf32 = (unsigned*)sbuf;

    const int tid  = threadIdx.x;
    const int wave = tid >> 6;
    const int lane = tid & 63;
    const int quad = lane >> 4;       // 0..3
    const int l15  = lane & 15;

    // =====================================================================
    // Phase 1: edge gather -> bf16 z-tile -> MFMA gated MLP -> atomic scatter
    // (identical to the round-0 kernel that measured 364 us @ 6 blocks/CU)
    // =====================================================================

    // ---- Stage W_f then W_s transposed to LDS, pull B-fragments to registers.
    short8 bF[5], bS[5];
#pragma unroll
    for (int mat = 0; mat < 2; ++mat) {
        const float* W = mat ? W_s : W_f;
        __syncthreads();
        for (int idx = tid; idx < IN_DIM * 64; idx += 256) {
            const int k = idx >> 6, n = idx & 63;
            sbuf[n * ZSTRIDE + k] = (short)f2bf(W[idx]);
        }
        __syncthreads();
#pragma unroll
        for (int kc = 0; kc < 5; ++kc) {
            const short8 b = *(const short8*)&sbuf[(16 * wave + l15) * ZSTRIDE + kc * 32 + quad * 8];
            if (mat) bS[kc] = b; else bF[kc] = b;
        }
    }

    const float bias_f = b_f[16 * wave + l15];
    const float bias_s = b_s[16 * wave + l15];
    float* const msgf  = out + 16 * wave + l15;   // per-lane feature column

    // Prefetch first tile's indices.
    int srcv = edge_src[blockIdx.x * 64 + lane];
    int tgtv = edge_tgt[blockIdx.x * 64 + lane];

    for (int t = blockIdx.x; t < N_TILES; t += GRID) {
        const int e0 = t * 64;

        __syncthreads();   // protect sbuf from previous iteration's readers

        // ---- Node rows (f32 -> bf16 inline): wave w stages edges [16w,16w+16).
#pragma unroll
        for (int i = 0; i < 8; ++i) {
            const int el   = i * 2 + (quad >> 1);
            const int half = quad & 1;
            const int sl   = 16 * wave + el;
            const int ns   = __shfl(srcv, sl);
            const int nt   = __shfl(tgtv, sl);
            const int node = half ? nt : ns;
            const float4 v = *(const float4*)&node_attrs[node * 64 + l15 * 4];
            uint2 o; o.x = pack2(v.x, v.y); o.y = pack2(v.z, v.w);
            *(uint2*)&sbuf32[sl * (ZSTRIDE / 2) + half * 32 + l15 * 2] = o;
        }
        // ---- Edge attrs (f32 -> bf16 inline): 512 float4 rows of 16B each.
#pragma unroll
        for (int i = 0; i < 2; ++i) {
            const int p  = i * 256 + tid;       // 0..511
            const int el = p >> 3, g = p & 7;
            const float4 v = *(const float4*)&edge_attrs[(size_t)(e0 + el) * 32 + g * 4];
            uint2 o; o.x = pack2(v.x, v.y); o.y = pack2(v.z, v.w);
            *(uint2*)&sbuf32[el * (ZSTRIDE / 2) + 64 + g * 2] = o;
        }

        // Prefetch next tile's indices (loads overlap the MFMA section).
        const int tn = t + GRID;
        int nsrc = 0, ntgt = 0;
        if (tn < N_TILES) {
            nsrc = edge_src[tn * 64 + lane];
            ntgt = edge_tgt[tn * 64 + lane];
        }
        __syncthreads();

        // ---- MFMA: 4 m-tiles x 5 k-chunks x 2 matrices, then fused epilogue.
#pragma unroll
        for (int mt = 0; mt < 4; ++mt) {
            f32x4 accF = {0.f, 0.f, 0.f, 0.f};
            f32x4 accS = {0.f, 0.f, 0.f, 0.f};
#pragma unroll
            for (int kc = 0; kc < 5; ++kc) {
                const short8 a = *(const short8*)&sbuf[(mt * 16 + l15) * ZSTRIDE + kc * 32 + quad * 8];
                accF = __builtin_amdgcn_mfma_f32_16x16x32_bf16(a, bF[kc], accF, 0, 0, 0);
                accS = __builtin_amdgcn_mfma_f32_16x16x32_bf16(a, bS[kc], accS, 0, 0, 0);
            }
            // C/D: col = l15 (feature), row = quad*4 + r (edge within m-tile)
#pragma unroll
            for (int r = 0; r < 4; ++r) {
                const float xf = accF[r] + bias_f;
                const float xs = accS[r] + bias_s;
                const float sig = __builtin_amdgcn_rcpf(1.0f + __expf(-xf));
                const float sp  = fmaxf(xs, 0.0f) + __logf(1.0f + __expf(-fabsf(xs)));
                const float h   = sig * sp;
                const int sl    = mt * 16 + quad * 4 + r;   // edge within tile
                const int node  = __shfl(srcv, sl);
                atomicAdd(&msgf[node * 64], h);
            }
        }

        srcv = nsrc;
        tgtv = ntgt;
    }

    // =====================================================================
    // Barrier 1: all messages accumulated.
    // =====================================================================
    grid_sync(&ctr[0]);

    // =====================================================================
    // Phase 2: BN batch stats. Grid-stride float4 sweep over msg.
    // =====================================================================
    {
        const int c  = tid & 15;
        const int r0 = blockIdx.x * 16 + (tid >> 4);
        float4 s = {0.f, 0.f, 0.f, 0.f};
        float4 q = {0.f, 0.f, 0.f, 0.f};
        for (int r = r0; r < N_NODES; r += GRID * 16) {
            const float4 v = *(const float4*)&out[(size_t)r * 64 + c * 4];
            s.x += v.x; s.y += v.y; s.z += v.z; s.w += v.w;
            q.x = fmaf(v.x, v.x, q.x);
            q.y = fmaf(v.y, v.y, q.y);
            q.z = fmaf(v.z, v.z, q.z);
            q.w = fmaf(v.w, v.w, q.w);
        }
        float4* rs = (float4*)sbuf;          // overlay: 256*16B = 4 KB
        float4* rq = rs + 256;               // next 4 KB (total 8 KB < 21.5 KB)
        rs[tid] = s;
        rq[tid] = q;
        __syncthreads();
        if (tid < 16) {
            float4 S = rs[tid];
            float4 Q = rq[tid];
#pragma unroll
            for (int k = 1; k < 16; ++k) {
                const float4 a = rs[k * 16 + tid];
                const float4 b = rq[k * 16 + tid];
                S.x += a.x; S.y += a.y; S.z += a.z; S.w += a.w;
                Q.x += b.x; Q.y += b.y; Q.z += b.z; Q.w += b.w;
            }
            atomicAdd(&stats[tid * 4 + 0], S.x);
            atomicAdd(&stats[tid * 4 + 1], S.y);
            atomicAdd(&stats[tid * 4 + 2], S.z);
            atomicAdd(&stats[tid * 4 + 3], S.w);
            atomicAdd(&stats[64 + tid * 4 + 0], Q.x);
            atomicAdd(&stats[64 + tid * 4 + 1], Q.y);
            atomicAdd(&stats[64 + tid * 4 + 2], Q.z);
            atomicAdd(&stats[64 + tid * 4 + 3], Q.w);
        }
    }

    // =====================================================================
    // Barrier 2: stats complete.
    // =====================================================================
    grid_sync(&ctr[1]);

    // =====================================================================
    // Phase 3: BN (training stats, biased var) + residual, in place.
    // =====================================================================
    {
        const float inv_n = 1.0f / (float)N_NODES;
        const int g0 = blockIdx.x * BLOCK + tid;
        for (int i = g0; i < N_NODES * NODE_F / 4; i += GRID * BLOCK) {
            const int idx = i * 4;
            const int f = idx & 63;

            const float4 m4 = *(const float4*)&out[idx];
            const float4 x4 = *(const float4*)&node_attrs[idx];

            float mean[4], rstd[4], gm[4], bt[4];
#pragma unroll
            for (int j = 0; j < 4; ++j) {
                mean[j] = stats[f + j] * inv_n;
                const float var = stats[64 + f + j] * inv_n - mean[j] * mean[j];
                rstd[j] = rsqrtf(var + 1e-5f);
                gm[j] = gamma[f + j];
                bt[j] = beta[f + j];
            }
            float4 o;
            o.x = x4.x + (m4.x - mean[0]) * rstd[0] * gm[0] + bt[0];
            o.y = x4.y + (m4.y - mean[1]) * rstd[1] * gm[1] + bt[1];
            o.z = x4.z + (m4.z - mean[2]) * rstd[2] * gm[2] + bt[2];
            o.w = x4.w + (m4.w - mean[3]) * rstd[3] * gm[3] + bt[3];
            *(float4*)&out[idx] = o;
        }
    }
}

extern "C" void kernel_launch(void* const* d_in, const int* in_sizes, int n_in,
                              void* d_out, int out_size, void* d_ws, size_t ws_size,
                              hipStream_t stream)
{
    const float* node_attrs = (const float*)d_in[0];
    const int*   edge_index = (const int*)d_in[1];   // [2, E] int32
    const float* edge_attrs = (const float*)d_in[2];
    const float* W_f   = (const float*)d_in[3];
    const float* b_f   = (const float*)d_in[4];
    const float* W_s   = (const float*)d_in[5];
    const float* b_s   = (const float*)d_in[6];
    const float* gamma = (const float*)d_in[7];
    const float* beta  = (const float*)d_in[8];

    float* out   = (float*)d_out;          // doubles as the msg accumulator
    float* stats = (float*)d_ws;           // 128 floats at ws+0
    int*   ctr   = (int*)((char*)d_ws + 512);   // 2 barrier counters

    const int* edge_src = edge_index;
    const int* edge_tgt = edge_index + N_EDGES;

    // Zero msg accumulator + stats + barrier counters (re-runs every replay).
    hipMemsetAsync(out, 0, (size_t)N_NODES * NODE_F * sizeof(float), stream);
    hipMemsetAsync(d_ws, 0, 1024, stream);

    fused_kernel<<<GRID, BLOCK, 0, stream>>>(
        node_attrs, edge_src, edge_tgt, edge_attrs,
        W_f, b_f, W_s, b_s, gamma, beta, out, stats, ctr);
}

// Round 5
// 866.029 us; speedup vs baseline: 1.8339x; 1.1158x over previous
//
#include <hip/hip_runtime.h>
#include <math.h>

#define N_NODES 100000
#define N_EDGES 1600000
#define NODE_F  64
#define IN_DIM  160          // 2*64 + 32
#define N_TILES 25000        // N_EDGES / 64
#define ZSTRIDE 168          // bf16 elems per z-row in LDS (336 B, 16B-aligned)
#define GRID    1536         // 6 blocks/CU x 256 CUs -- ALL co-resident
#define BLOCK   256

// ---- distributed grid barrier geometry ----
#define FLAG_GROUPS 192      // 1536 blocks / 8 per flag line
#define BSTATE_STRIDE 32768  // bytes per barrier instance
#define N_BARRIERS 3

typedef __attribute__((ext_vector_type(8))) short short8;   // 8 bf16 = 4 VGPRs
typedef __attribute__((ext_vector_type(4))) float f32x4;

// round-to-nearest-even f32 -> bf16 bits (scalar; used only in W staging)
static __device__ inline unsigned short f2bf(float f) {
    union { float f; unsigned u; } v; v.f = f;
    unsigned r = v.u + 0x7fffu + ((v.u >> 16) & 1u);
    return (unsigned short)(r >> 16);
}

// RNE-round two f32 and pack their high halves into one dword.
static __device__ inline unsigned pack2(float lo, float hi) {
    union { float f; unsigned u; } a, b; a.f = lo; b.f = hi;
    const unsigned ra = a.u + 0x7fffu + ((a.u >> 16) & 1u);
    const unsigned rb = b.u + 0x7fffu + ((b.u >> 16) & 1u);
    return __builtin_amdgcn_perm(rb, ra, 0x07060302u);
}

// Distributed device-wide barrier (round-4 post-mortem: a SINGLE polled
// cacheline saturates one L3/fabric slice at ~1.8G reads/s; the edge phase's
// atomic stream backs up behind it -> feedback stall. Here waiters poll 192
// distinct 128B-spaced flag lines, <=8 pollers each, s_sleep(64) cadence).
//
// State layout per barrier (within its 32KB slot, all zeroed per replay by
// the host-side ws memset -- self-cleaning across graph replays):
//   +0        : arrival counter (one line)
//   +128 ...  : FLAG_GROUPS flag lines, 128B apart
//
// Protocol:
//   __syncthreads()               - block sync; drains each wave's vmcnt
//   release fence (agent)         - buffer_wbl2 only: prior plain stores
//                                   become agent-visible; NO invalidate, so
//                                   co-resident blocks' L2 warmth survives
//   relaxed fetch_add(ctr)        - arrival; last arriver (prev==GRID-1)
//                                   relaxed-stores 1 to all 192 flag lines
//   waiters: relaxed poll own flag line + s_sleep(64)
//   acquire fence (agent)         - single buffer_inv AFTER release observed;
//                                   subsequent reads see remote atomics/stores
static __device__ __forceinline__ void grid_sync(char* bstate, int bid) {
    __syncthreads();
    if (threadIdx.x == 0) {
        int* ctr   = (int*)bstate;
        int* flags = (int*)(bstate + 128);
        __builtin_amdgcn_fence(__ATOMIC_RELEASE, "agent");
        const int prev = __hip_atomic_fetch_add(ctr, 1, __ATOMIC_RELAXED,
                                                __HIP_MEMORY_SCOPE_AGENT);
        if (prev == GRID - 1) {
            // last arriver: broadcast release to all flag lines
            for (int i = 0; i < FLAG_GROUPS; ++i)
                __hip_atomic_store(&flags[i * 32], 1, __ATOMIC_RELAXED,
                                   __HIP_MEMORY_SCOPE_AGENT);
        } else {
            int* myflag = &flags[(bid >> 3) * 32];
            int spins = 0;
            while (__hip_atomic_load(myflag, __ATOMIC_RELAXED,
                                     __HIP_MEMORY_SCOPE_AGENT) == 0) {
                __builtin_amdgcn_s_sleep(64);              // ~1.7 us/poll
                if (++spins > (1 << 18)) break;            // ~0.4 s failsafe
            }
        }
        __builtin_amdgcn_fence(__ATOMIC_ACQUIRE, "agent");
    }
    __syncthreads();
}

// ===========================================================================
// One persistent kernel:
//   [zero msg] -> barrier0 -> [edge gather->MFMA->atomic scatter] -> barrier1
//   -> [BN batch stats] -> barrier2 -> [BN + residual]
// 2 dispatches total (100KB ws memset + this kernel).
// ===========================================================================
__global__ __launch_bounds__(BLOCK, 6) void fused_kernel(
    const float* __restrict__ node_attrs,
    const int*   __restrict__ edge_src,
    const int*   __restrict__ edge_tgt,
    const float* __restrict__ edge_attrs,
    const float* __restrict__ W_f, const float* __restrict__ b_f,
    const float* __restrict__ W_s, const float* __restrict__ b_s,
    const float* __restrict__ gamma,
    const float* __restrict__ beta,
    float* __restrict__ out,            // msg accumulator, then final output
    float* __restrict__ stats,          // 128 floats in ws (zeroed by memset)
    char*  __restrict__ bstate)         // barrier state (zeroed by memset)
{
    __shared__ __align__(16) short sbuf[64 * ZSTRIDE];   // 21504 B
    unsigned* sbuf32 = (unsigned*)sbuf;

    const int tid = threadIdx.x;
    const int bid = blockIdx.x;
    const int wave = tid >> 6;
    const int lane = tid & 63;
    const int quad = lane >> 4;       // 0..3
    const int l15  = lane & 15;

    // =====================================================================
    // Phase 0: zero the msg accumulator (replaces the 25.6MB memset dispatch).
    // ~4 float4 stores/thread; barrier-0 skew is ~0 (all blocks just started).
    // =====================================================================
    {
        const float4 z = {0.f, 0.f, 0.f, 0.f};
        for (int i = bid * BLOCK + tid; i < N_NODES * NODE_F / 4; i += GRID * BLOCK)
            *(float4*)&out[(size_t)i * 4] = z;
    }
    grid_sync(bstate + 0 * BSTATE_STRIDE, bid);

    // =====================================================================
    // Phase 1: edge gather -> bf16 z-tile -> MFMA gated MLP -> atomic scatter
    // (byte-identical logic to the round-0 kernel: 364 us standalone)
    // =====================================================================

    // ---- Stage W_f then W_s transposed to LDS, pull B-fragments to registers.
    short8 bF[5], bS[5];
#pragma unroll
    for (int mat = 0; mat < 2; ++mat) {
        const float* W = mat ? W_s : W_f;
        __syncthreads();
        for (int idx = tid; idx < IN_DIM * 64; idx += 256) {
            const int k = idx >> 6, n = idx & 63;
            sbuf[n * ZSTRIDE + k] = (short)f2bf(W[idx]);
        }
        __syncthreads();
#pragma unroll
        for (int kc = 0; kc < 5; ++kc) {
            const short8 b = *(const short8*)&sbuf[(16 * wave + l15) * ZSTRIDE + kc * 32 + quad * 8];
            if (mat) bS[kc] = b; else bF[kc] = b;
        }
    }

    const float bias_f = b_f[16 * wave + l15];
    const float bias_s = b_s[16 * wave + l15];
    float* const msgf  = out + 16 * wave + l15;   // per-lane feature column

    // Prefetch first tile's indices.
    int srcv = edge_src[bid * 64 + lane];
    int tgtv = edge_tgt[bid * 64 + lane];

    for (int t = bid; t < N_TILES; t += GRID) {
        const int e0 = t * 64;

        __syncthreads();   // protect sbuf from previous iteration's readers

        // ---- Node rows (f32 -> bf16 inline): wave w stages edges [16w,16w+16).
#pragma unroll
        for (int i = 0; i < 8; ++i) {
            const int el   = i * 2 + (quad >> 1);
            const int half = quad & 1;
            const int sl   = 16 * wave + el;
            const int ns   = __shfl(srcv, sl);
            const int nt   = __shfl(tgtv, sl);
            const int node = half ? nt : ns;
            const float4 v = *(const float4*)&node_attrs[node * 64 + l15 * 4];
            uint2 o; o.x = pack2(v.x, v.y); o.y = pack2(v.z, v.w);
            *(uint2*)&sbuf32[sl * (ZSTRIDE / 2) + half * 32 + l15 * 2] = o;
        }
        // ---- Edge attrs (f32 -> bf16 inline): 512 float4 rows of 16B each.
#pragma unroll
        for (int i = 0; i < 2; ++i) {
            const int p  = i * 256 + tid;       // 0..511
            const int el = p >> 3, g = p & 7;
            const float4 v = *(const float4*)&edge_attrs[(size_t)(e0 + el) * 32 + g * 4];
            uint2 o; o.x = pack2(v.x, v.y); o.y = pack2(v.z, v.w);
            *(uint2*)&sbuf32[el * (ZSTRIDE / 2) + 64 + g * 2] = o;
        }

        // Prefetch next tile's indices (loads overlap the MFMA section).
        const int tn = t + GRID;
        int nsrc = 0, ntgt = 0;
        if (tn < N_TILES) {
            nsrc = edge_src[tn * 64 + lane];
            ntgt = edge_tgt[tn * 64 + lane];
        }
        __syncthreads();

        // ---- MFMA: 4 m-tiles x 5 k-chunks x 2 matrices, then fused epilogue.
#pragma unroll
        for (int mt = 0; mt < 4; ++mt) {
            f32x4 accF = {0.f, 0.f, 0.f, 0.f};
            f32x4 accS = {0.f, 0.f, 0.f, 0.f};
#pragma unroll
            for (int kc = 0; kc < 5; ++kc) {
                const short8 a = *(const short8*)&sbuf[(mt * 16 + l15) * ZSTRIDE + kc * 32 + quad * 8];
                accF = __builtin_amdgcn_mfma_f32_16x16x32_bf16(a, bF[kc], accF, 0, 0, 0);
                accS = __builtin_amdgcn_mfma_f32_16x16x32_bf16(a, bS[kc], accS, 0, 0, 0);
            }
            // C/D: col = l15 (feature), row = quad*4 + r (edge within m-tile)
#pragma unroll
            for (int r = 0; r < 4; ++r) {
                const float xf = accF[r] + bias_f;
                const float xs = accS[r] + bias_s;
                const float sig = __builtin_amdgcn_rcpf(1.0f + __expf(-xf));
                const float sp  = fmaxf(xs, 0.0f) + __logf(1.0f + __expf(-fabsf(xs)));
                const float h   = sig * sp;
                const int sl    = mt * 16 + quad * 4 + r;   // edge within tile
                const int node  = __shfl(srcv, sl);
                atomicAdd(&msgf[node * 64], h);   // fire-and-forget
            }
        }

        srcv = nsrc;
        tgtv = ntgt;
    }

    // =====================================================================
    // Barrier 1: all messages accumulated.
    // =====================================================================
    grid_sync(bstate + 1 * BSTATE_STRIDE, bid);

    // =====================================================================
    // Phase 2: BN batch stats. Grid-stride float4 sweep over msg.
    // =====================================================================
    {
        const int c  = tid & 15;
        const int r0 = bid * 16 + (tid >> 4);
        float4 s = {0.f, 0.f, 0.f, 0.f};
        float4 q = {0.f, 0.f, 0.f, 0.f};
        for (int r = r0; r < N_NODES; r += GRID * 16) {
            const float4 v = *(const float4*)&out[(size_t)r * 64 + c * 4];
            s.x += v.x; s.y += v.y; s.z += v.z; s.w += v.w;
            q.x = fmaf(v.x, v.x, q.x);
            q.y = fmaf(v.y, v.y, q.y);
            q.z = fmaf(v.z, v.z, q.z);
            q.w = fmaf(v.w, v.w, q.w);
        }
        float4* rs = (float4*)sbuf;          // overlay: 256*16B = 4 KB
        float4* rq = rs + 256;               // next 4 KB (total 8 KB < 21.5 KB)
        rs[tid] = s;
        rq[tid] = q;
        __syncthreads();
        if (tid < 16) {
            float4 S = rs[tid];
            float4 Q = rq[tid];
#pragma unroll
            for (int k = 1; k < 16; ++k) {
                const float4 a = rs[k * 16 + tid];
                const float4 b = rq[k * 16 + tid];
                S.x += a.x; S.y += a.y; S.z += a.z; S.w += a.w;
                Q.x += b.x; Q.y += b.y; Q.z += b.z; Q.w += b.w;
            }
            atomicAdd(&stats[tid * 4 + 0], S.x);
            atomicAdd(&stats[tid * 4 + 1], S.y);
            atomicAdd(&stats[tid * 4 + 2], S.z);
            atomicAdd(&stats[tid * 4 + 3], S.w);
            atomicAdd(&stats[64 + tid * 4 + 0], Q.x);
            atomicAdd(&stats[64 + tid * 4 + 1], Q.y);
            atomicAdd(&stats[64 + tid * 4 + 2], Q.z);
            atomicAdd(&stats[64 + tid * 4 + 3], Q.w);
        }
    }

    // =====================================================================
    // Barrier 2: stats complete.
    // =====================================================================
    grid_sync(bstate + 2 * BSTATE_STRIDE, bid);

    // =====================================================================
    // Phase 3: BN (training stats, biased var) + residual, in place.
    // =====================================================================
    {
        const float inv_n = 1.0f / (float)N_NODES;
        const int g0 = bid * BLOCK + tid;
        for (int i = g0; i < N_NODES * NODE_F / 4; i += GRID * BLOCK) {
            const int idx = i * 4;
            const int f = idx & 63;

            const float4 m4 = *(const float4*)&out[idx];
            const float4 x4 = *(const float4*)&node_attrs[idx];

            float mean[4], rstd[4], gm[4], bt[4];
#pragma unroll
            for (int j = 0; j < 4; ++j) {
                mean[j] = stats[f + j] * inv_n;
                const float var = stats[64 + f + j] * inv_n - mean[j] * mean[j];
                rstd[j] = rsqrtf(var + 1e-5f);
                gm[j] = gamma[f + j];
                bt[j] = beta[f + j];
            }
            float4 o;
            o.x = x4.x + (m4.x - mean[0]) * rstd[0] * gm[0] + bt[0];
            o.y = x4.y + (m4.y - mean[1]) * rstd[1] * gm[1] + bt[1];
            o.z = x4.z + (m4.z - mean[2]) * rstd[2] * gm[2] + bt[2];
            o.w = x4.w + (m4.w - mean[3]) * rstd[3] * gm[3] + bt[3];
            *(float4*)&out[idx] = o;
        }
    }
}

extern "C" void kernel_launch(void* const* d_in, const int* in_sizes, int n_in,
                              void* d_out, int out_size, void* d_ws, size_t ws_size,
                              hipStream_t stream)
{
    const float* node_attrs = (const float*)d_in[0];
    const int*   edge_index = (const int*)d_in[1];   // [2, E] int32
    const float* edge_attrs = (const float*)d_in[2];
    const float* W_f   = (const float*)d_in[3];
    const float* b_f   = (const float*)d_in[4];
    const float* W_s   = (const float*)d_in[5];
    const float* b_s   = (const float*)d_in[6];
    const float* gamma = (const float*)d_in[7];
    const float* beta  = (const float*)d_in[8];

    float* out   = (float*)d_out;               // msg accumulator + output
    float* stats = (float*)d_ws;                // 128 floats at ws+0
    char*  bstate = (char*)d_ws + 4096;         // 3 x 32KB barrier slots

    const int* edge_src = edge_index;
    const int* edge_tgt = edge_index + N_EDGES;

    // One small memset: stats + all barrier state (self-cleaning per replay).
    hipMemsetAsync(d_ws, 0, 4096 + N_BARRIERS * BSTATE_STRIDE, stream);

    fused_kernel<<<GRID, BLOCK, 0, stream>>>(
        node_attrs, edge_src, edge_tgt, edge_attrs,
        W_f, b_f, W_s, b_s, gamma, beta, out, stats, bstate);
}

// Round 6
// 716.191 us; speedup vs baseline: 2.2176x; 1.2092x over previous
//
#include <hip/hip_runtime.h>
#include <math.h>

#define N_NODES 100000
#define N_EDGES 1600000
#define NODE_F  64
#define IN_DIM  160          // 2*64 + 32
#define N_TILES 25000        // N_EDGES / 64
#define ZSTRIDE 168          // bf16 elems per z-row (fallback kernel)
#define EDGE_GRID 1536       // fallback: 6 blocks/CU
#define PQ_GRID  2048        // edge_pq: 8 blocks/CU (tiny LDS, low VGPR)
#define PRE_GRID 512
#define PRE_TILES 1563       // ceil(100000/64)

typedef __attribute__((ext_vector_type(8))) short short8;   // 8 bf16 = 4 VGPRs
typedef __attribute__((ext_vector_type(4))) float f32x4;

// round-to-nearest-even f32 -> bf16 bits (scalar; staging only)
static __device__ inline unsigned short f2bf(float f) {
    union { float f; unsigned u; } v; v.f = f;
    unsigned r = v.u + 0x7fffu + ((v.u >> 16) & 1u);
    return (unsigned short)(r >> 16);
}

// RNE-round two f32 and pack their high halves into one dword.
static __device__ inline unsigned pack2(float lo, float hi) {
    union { float f; unsigned u; } a, b; a.f = lo; b.f = hi;
    const unsigned ra = a.u + 0x7fffu + ((a.u >> 16) & 1u);
    const unsigned rb = b.u + 0x7fffu + ((b.u >> 16) & 1u);
    return __builtin_amdgcn_perm(rb, ra, 0x07060302u);
}

// ===========================================================================
// Precompute kernel: PS[n][2f+m] = x_n @ Wm[0:64, f]   (m: 0=W_f, 1=W_s)
//                    QT[n][2f+m] = x_n @ Wm[64:128, f]
// Interleaved (f-major pairs) so the edge epilogue loads one float2 per
// (edge-end, feature): 16 lanes x 8B = 128B coalesced per quad.
// 3.3 GFLOP GEMM replacing 52 GFLOP of per-edge node-part MFMA work.
// ===========================================================================
__global__ __launch_bounds__(256, 3) void precompute_kernel(
    const float* __restrict__ X,
    const float* __restrict__ W_f, const float* __restrict__ W_s,
    float* __restrict__ PS, float* __restrict__ QT)
{
    // WT_PS/WT_QT: [col 0..127][k 0..63] bf16, pad 68. XL: [row][k] pad 72.
    __shared__ __align__(16) short wtps[128 * 68];   // 17408 B
    __shared__ __align__(16) short wtqt[128 * 68];   // 17408 B
    __shared__ __align__(16) short xl[64 * 72];      //  9216 B
    unsigned* xl32 = (unsigned*)xl;

    const int tid  = threadIdx.x;
    const int wave = tid >> 6;
    const int lane = tid & 63;
    const int quad = lane >> 4;
    const int l15  = lane & 15;

    // ---- Stage interleaved transposed W (once per block).
    for (int idx = tid; idx < 128 * 64; idx += 256) {
        const int c = idx >> 6;          // 0..127 output col
        const int k = idx & 63;          // k within part
        const int j = c >> 1;            // feature
        const float* W = (c & 1) ? W_s : W_f;
        wtps[c * 68 + k] = (short)f2bf(W[k * 64 + j]);
        wtqt[c * 68 + k] = (short)f2bf(W[(k + 64) * 64 + j]);
    }
    __syncthreads();

    // ---- B fragments for this wave: matrix sel = wave>>1, colbase=(wave&1)*64
    const short* wt = (wave >> 1) ? wtqt : wtps;
    const int colbase = (wave & 1) * 64;
    float* const OUT = (wave >> 1) ? QT : PS;

    short8 bfr[4][2];
#pragma unroll
    for (int nt = 0; nt < 4; ++nt)
#pragma unroll
        for (int kc = 0; kc < 2; ++kc)
            bfr[nt][kc] = *(const short8*)&wt[(colbase + nt * 16 + l15) * 68 + kc * 32 + quad * 8];

    for (int t = blockIdx.x; t < PRE_TILES; t += PRE_GRID) {
        const int n0 = t * 64;
        __syncthreads();
        // ---- Stage X tile (64 rows x 64 f32 -> bf16), guarded tail.
        for (int idx = tid; idx < 64 * 16; idx += 256) {
            const int row = idx >> 4, c4 = idx & 15;
            float4 v = {0.f, 0.f, 0.f, 0.f};
            if (n0 + row < N_NODES)
                v = *(const float4*)&X[(size_t)(n0 + row) * 64 + c4 * 4];
            uint2 o; o.x = pack2(v.x, v.y); o.y = pack2(v.z, v.w);
            *(uint2*)&xl32[row * 36 + c4 * 2] = o;
        }
        __syncthreads();

#pragma unroll
        for (int mt = 0; mt < 4; ++mt) {
            short8 a0 = *(const short8*)&xl[(mt * 16 + l15) * 72 + 0 * 32 + quad * 8];
            short8 a1 = *(const short8*)&xl[(mt * 16 + l15) * 72 + 1 * 32 + quad * 8];
#pragma unroll
            for (int nt = 0; nt < 4; ++nt) {
                f32x4 acc = {0.f, 0.f, 0.f, 0.f};
                acc = __builtin_amdgcn_mfma_f32_16x16x32_bf16(a0, bfr[nt][0], acc, 0, 0, 0);
                acc = __builtin_amdgcn_mfma_f32_16x16x32_bf16(a1, bfr[nt][1], acc, 0, 0, 0);
#pragma unroll
                for (int r = 0; r < 4; ++r) {
                    const int node = n0 + mt * 16 + quad * 4 + r;
                    if (node < N_NODES)
                        OUT[(size_t)node * 128 + colbase + nt * 16 + l15] = acc[r];
                }
            }
        }
    }
}

// ===========================================================================
// Edge kernel (PQ form): stage edge_attrs tile -> K=32 MFMA (edge part only)
// -> epilogue: gather precomputed node parts (2 x float2), activation,
// atomic scatter. No node-row staging, 8 MFMA/tile instead of 40.
// ===========================================================================
__global__ __launch_bounds__(256, 8) void edge_pq_kernel(
    const float* __restrict__ PS,
    const float* __restrict__ QT,
    const int*   __restrict__ edge_src,
    const int*   __restrict__ edge_tgt,
    const float* __restrict__ edge_attrs,
    const float* __restrict__ W_f, const float* __restrict__ b_f,
    const float* __restrict__ W_s, const float* __restrict__ b_s,
    float* __restrict__ msg)
{
    __shared__ __align__(16) short ebuf[64 * 40];   // edge tile, 5120 B
    __shared__ __align__(16) short wet[64 * 72];    // [col][2x32k] W_e^T, 9216 B

    const int tid  = threadIdx.x;
    const int wave = tid >> 6;
    const int lane = tid & 63;
    const int quad = lane >> 4;
    const int l15  = lane & 15;

    // ---- Stage W edge-part transposed: wet[c][k] (F) / wet[c][32+k] (S).
    for (int idx = tid; idx < 64 * 32; idx += 256) {
        const int c = idx >> 5, k = idx & 31;
        wet[c * 72 + k]      = (short)f2bf(W_f[(k + 128) * 64 + c]);
        wet[c * 72 + 32 + k] = (short)f2bf(W_s[(k + 128) * 64 + c]);
    }
    __syncthreads();
    const short8 bFe = *(const short8*)&wet[(16 * wave + l15) * 72 + quad * 8];
    const short8 bSe = *(const short8*)&wet[(16 * wave + l15) * 72 + 32 + quad * 8];

    const float bias_f = b_f[16 * wave + l15];
    const float bias_s = b_s[16 * wave + l15];
    const int   fcol2  = 2 * (16 * wave + l15);     // float2 offset into PS/QT rows
    float* const msgf  = msg + 16 * wave + l15;

    // staging geometry: 4 threads per edge, 8 feats each
    const int sel = tid >> 2;        // edge within tile
    const int sg  = tid & 3;         // 8-feature group

    // Prefetch first tile's indices.
    int srcv = edge_src[blockIdx.x * 64 + lane];
    int tgtv = edge_tgt[blockIdx.x * 64 + lane];

    for (int t = blockIdx.x; t < N_TILES; t += PQ_GRID) {
        const int e0 = t * 64;

        __syncthreads();   // protect ebuf from previous iteration's readers

        // ---- Edge attrs (f32 -> bf16): 64 x 32, fully coalesced.
        {
            const float4 v0 = *(const float4*)&edge_attrs[(size_t)(e0 + sel) * 32 + sg * 8];
            const float4 v1 = *(const float4*)&edge_attrs[(size_t)(e0 + sel) * 32 + sg * 8 + 4];
            short8 o;
            unsigned* o32 = (unsigned*)&o;
            o32[0] = pack2(v0.x, v0.y); o32[1] = pack2(v0.z, v0.w);
            o32[2] = pack2(v1.x, v1.y); o32[3] = pack2(v1.z, v1.w);
            *(short8*)&ebuf[sel * 40 + sg * 8] = o;
        }

        // Prefetch next tile's indices (overlap MFMA+epilogue).
        const int tn = t + PQ_GRID;
        int nsrc = 0, ntgt = 0;
        if (tn < N_TILES) {
            nsrc = edge_src[tn * 64 + lane];
            ntgt = edge_tgt[tn * 64 + lane];
        }
        __syncthreads();

        // ---- 4 m-tiles x 1 k-chunk (K=32) x 2 matrices + fused epilogue.
#pragma unroll
        for (int mt = 0; mt < 4; ++mt) {
            const short8 a = *(const short8*)&ebuf[(mt * 16 + l15) * 40 + quad * 8];
            f32x4 accF = {0.f, 0.f, 0.f, 0.f};
            f32x4 accS = {0.f, 0.f, 0.f, 0.f};
            accF = __builtin_amdgcn_mfma_f32_16x16x32_bf16(a, bFe, accF, 0, 0, 0);
            accS = __builtin_amdgcn_mfma_f32_16x16x32_bf16(a, bSe, accS, 0, 0, 0);
#pragma unroll
            for (int r = 0; r < 4; ++r) {
                const int e = mt * 16 + quad * 4 + r;     // edge within tile
                const int s = __shfl(srcv, e);
                const int g = __shfl(tgtv, e);
                const float2 ps = *(const float2*)&PS[(size_t)s * 128 + fcol2];
                const float2 qt = *(const float2*)&QT[(size_t)g * 128 + fcol2];
                const float xf = accF[r] + ps.x + qt.x + bias_f;
                const float xs = accS[r] + ps.y + qt.y + bias_s;
                const float sig = __builtin_amdgcn_rcpf(1.0f + __expf(-xf));
                const float sp  = fmaxf(xs, 0.0f) + __logf(1.0f + __expf(-fabsf(xs)));
                atomicAdd(&msgf[s * 64], sig * sp);       // fire-and-forget
            }
        }

        srcv = nsrc;
        tgtv = ntgt;
    }
}

// ===========================================================================
// Fallback edge kernel (round-0 form, 364 us) if workspace < 102.4 MB.
// ===========================================================================
__global__ __launch_bounds__(256, 6) void edge_kernel(
    const float* __restrict__ node_attrs,
    const int*   __restrict__ edge_src,
    const int*   __restrict__ edge_tgt,
    const float* __restrict__ edge_attrs,
    const float* __restrict__ W_f, const float* __restrict__ b_f,
    const float* __restrict__ W_s, const float* __restrict__ b_s,
    float* __restrict__ msg)
{
    __shared__ __align__(16) short sbuf[64 * ZSTRIDE];
    unsigned* sbuf32 = (unsigned*)sbuf;

    const int tid  = threadIdx.x;
    const int wave = tid >> 6;
    const int lane = tid & 63;
    const int quad = lane >> 4;
    const int l15  = lane & 15;

    short8 bF[5], bS[5];
#pragma unroll
    for (int mat = 0; mat < 2; ++mat) {
        const float* W = mat ? W_s : W_f;
        __syncthreads();
        for (int idx = tid; idx < IN_DIM * 64; idx += 256) {
            const int k = idx >> 6, n = idx & 63;
            sbuf[n * ZSTRIDE + k] = (short)f2bf(W[idx]);
        }
        __syncthreads();
#pragma unroll
        for (int kc = 0; kc < 5; ++kc) {
            const short8 b = *(const short8*)&sbuf[(16 * wave + l15) * ZSTRIDE + kc * 32 + quad * 8];
            if (mat) bS[kc] = b; else bF[kc] = b;
        }
    }

    const float bias_f = b_f[16 * wave + l15];
    const float bias_s = b_s[16 * wave + l15];
    float* const msgf  = msg + 16 * wave + l15;

    int srcv = edge_src[blockIdx.x * 64 + lane];
    int tgtv = edge_tgt[blockIdx.x * 64 + lane];

    for (int t = blockIdx.x; t < N_TILES; t += EDGE_GRID) {
        const int e0 = t * 64;
        __syncthreads();
#pragma unroll
        for (int i = 0; i < 8; ++i) {
            const int el   = i * 2 + (quad >> 1);
            const int half = quad & 1;
            const int sl   = 16 * wave + el;
            const int ns   = __shfl(srcv, sl);
            const int nt   = __shfl(tgtv, sl);
            const int node = half ? nt : ns;
            const float4 v = *(const float4*)&node_attrs[node * 64 + l15 * 4];
            uint2 o; o.x = pack2(v.x, v.y); o.y = pack2(v.z, v.w);
            *(uint2*)&sbuf32[sl * (ZSTRIDE / 2) + half * 32 + l15 * 2] = o;
        }
#pragma unroll
        for (int i = 0; i < 2; ++i) {
            const int p  = i * 256 + tid;
            const int el = p >> 3, g = p & 7;
            const float4 v = *(const float4*)&edge_attrs[(size_t)(e0 + el) * 32 + g * 4];
            uint2 o; o.x = pack2(v.x, v.y); o.y = pack2(v.z, v.w);
            *(uint2*)&sbuf32[el * (ZSTRIDE / 2) + 64 + g * 2] = o;
        }
        const int tn = t + EDGE_GRID;
        int nsrc = 0, ntgt = 0;
        if (tn < N_TILES) {
            nsrc = edge_src[tn * 64 + lane];
            ntgt = edge_tgt[tn * 64 + lane];
        }
        __syncthreads();
#pragma unroll
        for (int mt = 0; mt < 4; ++mt) {
            f32x4 accF = {0.f, 0.f, 0.f, 0.f};
            f32x4 accS = {0.f, 0.f, 0.f, 0.f};
#pragma unroll
            for (int kc = 0; kc < 5; ++kc) {
                const short8 a = *(const short8*)&sbuf[(mt * 16 + l15) * ZSTRIDE + kc * 32 + quad * 8];
                accF = __builtin_amdgcn_mfma_f32_16x16x32_bf16(a, bF[kc], accF, 0, 0, 0);
                accS = __builtin_amdgcn_mfma_f32_16x16x32_bf16(a, bS[kc], accS, 0, 0, 0);
            }
#pragma unroll
            for (int r = 0; r < 4; ++r) {
                const float xf = accF[r] + bias_f;
                const float xs = accS[r] + bias_s;
                const float sig = __builtin_amdgcn_rcpf(1.0f + __expf(-xf));
                const float sp  = fmaxf(xs, 0.0f) + __logf(1.0f + __expf(-fabsf(xs)));
                const float h   = sig * sp;
                const int sl    = mt * 16 + quad * 4 + r;
                const int node  = __shfl(srcv, sl);
                atomicAdd(&msgf[node * 64], h);
            }
        }
        srcv = nsrc;
        tgtv = ntgt;
    }
}

// ---------------------------------------------------------------------------
// Phase 2: per-feature sum / sumsq over nodes (round-0 version).
// ---------------------------------------------------------------------------
#define STATS_BLOCKS 400
__global__ __launch_bounds__(256) void stats_kernel(
    const float* __restrict__ msg, float* __restrict__ stats)
{
    const int tid = threadIdx.x;
    const int f = tid & 63;
    const int g = tid >> 6;
    float s = 0.0f, q = 0.0f;
    for (int r = blockIdx.x * 4 + g; r < N_NODES; r += STATS_BLOCKS * 4) {
        const float v = msg[r * 64 + f];
        s += v;
        q = fmaf(v, v, q);
    }
    __shared__ float rs[4][64];
    __shared__ float rq[4][64];
    rs[g][f] = s;
    rq[g][f] = q;
    __syncthreads();
    if (tid < 64) {
        const float ss = rs[0][f] + rs[1][f] + rs[2][f] + rs[3][f];
        const float qq = rq[0][f] + rq[1][f] + rq[2][f] + rq[3][f];
        atomicAdd(&stats[f], ss);
        atomicAdd(&stats[64 + f], qq);
    }
}

// ---------------------------------------------------------------------------
// Phase 3: in-place BN (training stats, biased var) + residual.
// ---------------------------------------------------------------------------
__global__ __launch_bounds__(256) void norm_kernel(
    const float* __restrict__ node_attrs,
    const float* __restrict__ stats,
    const float* __restrict__ gamma,
    const float* __restrict__ beta,
    float* __restrict__ out)
{
    const int i = blockIdx.x * blockDim.x + threadIdx.x;
    const int idx = i * 4;
    if (idx >= N_NODES * 64) return;
    const int f = idx & 63;
    const float inv_n = 1.0f / (float)N_NODES;

    const float4 m4 = *(const float4*)&out[idx];
    const float4 x4 = *(const float4*)&node_attrs[idx];

    float mean[4], rstd[4], gm[4], bt[4];
#pragma unroll
    for (int j = 0; j < 4; ++j) {
        mean[j] = stats[f + j] * inv_n;
        const float var = stats[64 + f + j] * inv_n - mean[j] * mean[j];
        rstd[j] = rsqrtf(var + 1e-5f);
        gm[j] = gamma[f + j];
        bt[j] = beta[f + j];
    }
    float4 o;
    o.x = x4.x + (m4.x - mean[0]) * rstd[0] * gm[0] + bt[0];
    o.y = x4.y + (m4.y - mean[1]) * rstd[1] * gm[1] + bt[1];
    o.z = x4.z + (m4.z - mean[2]) * rstd[2] * gm[2] + bt[2];
    o.w = x4.w + (m4.w - mean[3]) * rstd[3] * gm[3] + bt[3];
    *(float4*)&out[idx] = o;
}

extern "C" void kernel_launch(void* const* d_in, const int* in_sizes, int n_in,
                              void* d_out, int out_size, void* d_ws, size_t ws_size,
                              hipStream_t stream)
{
    const float* node_attrs = (const float*)d_in[0];
    const int*   edge_index = (const int*)d_in[1];   // [2, E] int32
    const float* edge_attrs = (const float*)d_in[2];
    const float* W_f   = (const float*)d_in[3];
    const float* b_f   = (const float*)d_in[4];
    const float* W_s   = (const float*)d_in[5];
    const float* b_s   = (const float*)d_in[6];
    const float* gamma = (const float*)d_in[7];
    const float* beta  = (const float*)d_in[8];

    float* out   = (float*)d_out;          // doubles as the msg accumulator
    float* stats = (float*)d_ws;           // 128 floats at ws+0

    // Workspace: PS at +4096 (100000*128 f32 = 51.2MB), QT after.
    float* PS = (float*)((char*)d_ws + 4096);
    float* QT = PS + (size_t)N_NODES * 128;
    const size_t WS_NEED = 4096 + 2ull * N_NODES * 128 * sizeof(float); // ~102.4MB

    const int* edge_src = edge_index;
    const int* edge_tgt = edge_index + N_EDGES;

    hipMemsetAsync(out, 0, (size_t)N_NODES * NODE_F * sizeof(float), stream);
    hipMemsetAsync(stats, 0, 128 * sizeof(float), stream);

    if (ws_size >= WS_NEED) {
        precompute_kernel<<<PRE_GRID, 256, 0, stream>>>(node_attrs, W_f, W_s, PS, QT);
        edge_pq_kernel<<<PQ_GRID, 256, 0, stream>>>(
            PS, QT, edge_src, edge_tgt, edge_attrs, W_f, b_f, W_s, b_s, out);
    } else {
        edge_kernel<<<EDGE_GRID, 256, 0, stream>>>(
            node_attrs, edge_src, edge_tgt, edge_attrs, W_f, b_f, W_s, b_s, out);
    }

    stats_kernel<<<STATS_BLOCKS, 256, 0, stream>>>(out, stats);

    norm_kernel<<<(N_NODES * NODE_F / 4 + 255) / 256, 256, 0, stream>>>(
        node_attrs, stats, gamma, beta, out);
}